// Round 7
// baseline (313.095 us; speedup 1.0000x reference)
//
#include <hip/hip_runtime.h>

#define F 128
#define RANGE 12500   // nodes per LDS-histogram range

typedef unsigned short ushort_t;

__device__ inline float bf_lo(unsigned u) { return __uint_as_float(u << 16); }
__device__ inline float bf_hi(unsigned u) { return __uint_as_float(u & 0xffff0000u); }
__device__ inline ushort_t f2bf(float f) {          // RNE float->bf16
    unsigned u = __float_as_uint(f);
    return (ushort_t)((u + 0x7fff + ((u >> 16) & 1)) >> 16);
}

// ---- 1. fused src+dst LDS histograms (100 KB LDS, no global atomics) ----
__global__ __launch_bounds__(256)
void hist_both_kernel(const int* __restrict__ src, const int* __restrict__ dst,
                      int* __restrict__ part_src, int* __restrict__ part_dst,
                      int E, int S, int SLICE) {
    __shared__ int hs[RANGE];
    __shared__ int hd[RANGE];
    int b = blockIdx.x, t = threadIdx.x;
    int r = b / S, s = b % S;
    int lo = r * RANGE;
    for (int i = t; i < RANGE; i += 256) { hs[i] = 0; hd[i] = 0; }
    __syncthreads();
    int e0 = s * SLICE, e1 = min(e0 + SLICE, E);
    for (int e = e0 + t; e < e1; e += 256) {
        int vs = src[e] - lo;
        int vd = dst[e] - lo;
        if ((unsigned)vs < (unsigned)RANGE) atomicAdd(&hs[vs], 1);
        if ((unsigned)vd < (unsigned)RANGE) atomicAdd(&hd[vd], 1);
    }
    __syncthreads();
    int* ops = part_src + (size_t)b * RANGE;
    int* opd = part_dst + (size_t)b * RANGE;
    for (int i = t; i < RANGE; i += 256) { ops[i] = hs[i]; opd[i] = hd[i]; }
}

// ---- 2. fused reduction: inv_out, cnt_in, per-slice prefix, block sums ----
// one block = 1024 nodes (4 per thread); bsum[b] = sum of cnt_in over block
__global__ __launch_bounds__(256)
void reduce_all_kernel(const int* __restrict__ part_src, int* __restrict__ part_dst,
                       float* __restrict__ inv_out, int* __restrict__ cnt_in,
                       int* __restrict__ bsum, int S, int N) {
    int b = blockIdx.x, t = threadIdx.x;
    int blocal = 0;
    #pragma unroll
    for (int j = 0; j < 4; ++j) {
        int v = b * 1024 + t * 4 + j;
        if (v < N) {
            int r = v / RANGE, vp = v % RANGE;
            const int* ps = part_src + (size_t)r * S * RANGE + vp;
            int sum = 0;
            for (int s = 0; s < S; ++s) sum += ps[(size_t)s * RANGE];
            inv_out[v] = rsqrtf(fmaxf((float)sum, 1.0f));
            int* pd = part_dst + (size_t)r * S * RANGE + vp;
            int run = 0;
            for (int s = 0; s < S; ++s) {
                int tv = pd[(size_t)s * RANGE];
                pd[(size_t)s * RANGE] = run;
                run += tv;
            }
            cnt_in[v] = run;
            blocal += run;
        }
    }
    #pragma unroll
    for (int off = 32; off > 0; off >>= 1) blocal += __shfl_down(blocal, off);
    __shared__ int ws[4];
    int lane = t & 63, w = t >> 6;
    if (lane == 0) ws[w] = blocal;
    __syncthreads();
    if (t == 0) bsum[b] = ws[0] + ws[1] + ws[2] + ws[3];
}

// ---- 3. row offsets: base = sum(bsum[0..b)), then block-local scan ----
// requires gridDim.x <= 64
__global__ __launch_bounds__(256)
void scan_rows_kernel(const int* __restrict__ cnt_in, const int* __restrict__ bsum,
                      int* __restrict__ row_off, int N, int E) {
    int b = blockIdx.x, t = threadIdx.x;
    __shared__ int sbase;
    if (t < 64) {
        int v = (t < b) ? bsum[t] : 0;
        #pragma unroll
        for (int off = 32; off > 0; off >>= 1) v += __shfl_down(v, off);
        if (t == 0) sbase = v;
    }
    if (b == 0 && t == 0) row_off[N] = E;
    __syncthreads();
    int base = sbase;

    int i0 = b * 1024 + t * 4;
    int v[4]; int s = 0;
    #pragma unroll
    for (int j = 0; j < 4; ++j) { int i = i0 + j; v[j] = (i < N) ? cnt_in[i] : 0; s += v[j]; }
    int lane = t & 63, w = t >> 6;
    int incl = s;
    #pragma unroll
    for (int off = 1; off < 64; off <<= 1) {
        int u = __shfl_up(incl, off);
        if (lane >= off) incl += u;
    }
    __shared__ int wsum[4];
    if (lane == 63) wsum[w] = incl;
    __syncthreads();
    int wbase = 0;
    #pragma unroll
    for (int j = 0; j < 4; ++j) if (j < w) wbase += wsum[j];
    int run = base + wbase + (incl - s);
    #pragma unroll
    for (int j = 0; j < 4; ++j) {
        int i = i0 + j;
        if (i < N) { row_off[i] = run; run += v[j]; }
    }
}

// ---- 4. CSR fill with LDS cursors (no global atomics) ----
__global__ __launch_bounds__(256)
void fill_kernel(const int* __restrict__ src, const int* __restrict__ dst,
                 const int* __restrict__ row_off, const int* __restrict__ part_dst,
                 int* __restrict__ csr_src, int E, int S, int SLICE, int N) {
    __shared__ int cur[RANGE];
    int b = blockIdx.x, t = threadIdx.x;
    int r = b / S, s = b % S;
    int lo = r * RANGE;
    int hi = min(lo + RANGE, N);
    const int* pp = part_dst + (size_t)b * RANGE;
    for (int i = t; i < hi - lo; i += 256) cur[i] = row_off[lo + i] + pp[i];
    __syncthreads();
    int e0 = s * SLICE, e1 = min(e0 + SLICE, E);
    for (int e = e0 + t; e < e1; e += 256) {
        int d = dst[e] - lo;
        if ((unsigned)d < (unsigned)(hi - lo)) {
            int pos = atomicAdd(&cur[d], 1);       // LDS atomic
            csr_src[pos] = src[e];                 // plain store
        }
    }
}

// ---- 5. GEMM: Y = bf16( (x @ W) * inv_out[row] ) ----
__global__ __launch_bounds__(256)
void gemm_kernel(const float* __restrict__ x, const float* __restrict__ W,
                 const float* __restrict__ inv_out, ushort_t* __restrict__ Y, int N) {
    __shared__ float Ws[32 * 128];
    __shared__ float Hs[32 * 36];
    const int t = threadIdx.x;
    const int r0 = blockIdx.x * 32;
    const int tc = t & 31;
    const int tr = t >> 5;

    float4 a0 = {0,0,0,0}, a1 = {0,0,0,0}, a2 = {0,0,0,0}, a3 = {0,0,0,0};

    for (int kc = 0; kc < 4; ++kc) {
        const int k0 = kc * 32;
        #pragma unroll
        for (int j = 0; j < 16; ++j) {
            int i = t + 256 * j;
            int kk = i >> 7, c = i & 127;
            Ws[kk * 128 + c] = W[(k0 + kk) * F + c];
        }
        #pragma unroll
        for (int j = 0; j < 4; ++j) {
            int i = t + 256 * j;
            int r = i >> 5, kk = i & 31;
            int row = min(r0 + r, N - 1);
            Hs[kk * 36 + r] = x[(long long)row * F + k0 + kk];
        }
        __syncthreads();
        #pragma unroll
        for (int kk = 0; kk < 32; ++kk) {
            float4 hv = *(const float4*)&Hs[kk * 36 + 4 * tr];
            float4 wv = *(const float4*)&Ws[kk * 128 + 4 * tc];
            a0.x = fmaf(hv.x, wv.x, a0.x); a0.y = fmaf(hv.x, wv.y, a0.y);
            a0.z = fmaf(hv.x, wv.z, a0.z); a0.w = fmaf(hv.x, wv.w, a0.w);
            a1.x = fmaf(hv.y, wv.x, a1.x); a1.y = fmaf(hv.y, wv.y, a1.y);
            a1.z = fmaf(hv.y, wv.z, a1.z); a1.w = fmaf(hv.y, wv.w, a1.w);
            a2.x = fmaf(hv.z, wv.x, a2.x); a2.y = fmaf(hv.z, wv.y, a2.y);
            a2.z = fmaf(hv.z, wv.z, a2.z); a2.w = fmaf(hv.z, wv.w, a2.w);
            a3.x = fmaf(hv.w, wv.x, a3.x); a3.y = fmaf(hv.w, wv.y, a3.y);
            a3.z = fmaf(hv.w, wv.z, a3.z); a3.w = fmaf(hv.w, wv.w, a3.w);
        }
        __syncthreads();
    }

    float4 acc[4] = {a0, a1, a2, a3};
    #pragma unroll
    for (int i = 0; i < 4; ++i) {
        int row = r0 + 4 * tr + i;
        if (row < N) {
            float sc = inv_out[row];
            float4 o = acc[i];
            ushort4 yv;
            yv.x = f2bf(o.x * sc);
            yv.y = f2bf(o.y * sc);
            yv.z = f2bf(o.z * sc);
            yv.w = f2bf(o.w * sc);
            *(ushort4*)&Y[(long long)row * F + 4 * tc] = yv;
        }
    }
}

// ---- 6. gather: wave per node; quarter-waves (16 lanes x uint4 = 8 bf16) ----
__global__ __launch_bounds__(256)
void gather_kernel(const ushort_t* __restrict__ Y, const int* __restrict__ csr_src,
                   const int* __restrict__ row_off, const float* __restrict__ bias,
                   float* __restrict__ out, int N) {
    int v = blockIdx.x * 4 + (threadIdx.x >> 6);
    if (v >= N) return;
    int lane = threadIdx.x & 63;
    int q = lane >> 4;        // quarter 0..3
    int l16 = lane & 15;      // feats 8*l16 .. 8*l16+7
    int beg = row_off[v], end = row_off[v + 1];
    float accA[8] = {0,0,0,0,0,0,0,0};
    float accB[8] = {0,0,0,0,0,0,0,0};
    int j = beg + q;
    for (; j + 4 < end; j += 8) {
        int s0 = csr_src[j];
        int s1 = csr_src[j + 4];
        uint4 u0 = *(const uint4*)(Y + (size_t)s0 * F + l16 * 8);
        uint4 u1 = *(const uint4*)(Y + (size_t)s1 * F + l16 * 8);
        accA[0] += bf_lo(u0.x); accA[1] += bf_hi(u0.x);
        accA[2] += bf_lo(u0.y); accA[3] += bf_hi(u0.y);
        accA[4] += bf_lo(u0.z); accA[5] += bf_hi(u0.z);
        accA[6] += bf_lo(u0.w); accA[7] += bf_hi(u0.w);
        accB[0] += bf_lo(u1.x); accB[1] += bf_hi(u1.x);
        accB[2] += bf_lo(u1.y); accB[3] += bf_hi(u1.y);
        accB[4] += bf_lo(u1.z); accB[5] += bf_hi(u1.z);
        accB[6] += bf_lo(u1.w); accB[7] += bf_hi(u1.w);
    }
    if (j < end) {
        int s0 = csr_src[j];
        uint4 u0 = *(const uint4*)(Y + (size_t)s0 * F + l16 * 8);
        accA[0] += bf_lo(u0.x); accA[1] += bf_hi(u0.x);
        accA[2] += bf_lo(u0.y); accA[3] += bf_hi(u0.y);
        accA[4] += bf_lo(u0.z); accA[5] += bf_hi(u0.z);
        accA[6] += bf_lo(u0.w); accA[7] += bf_hi(u0.w);
    }
    #pragma unroll
    for (int i = 0; i < 8; ++i) {
        float a = accA[i] + accB[i];
        a += __shfl_xor(a, 16);
        a += __shfl_xor(a, 32);
        accA[i] = a;
    }
    if (q == 0) {
        float invd = rsqrtf(fmaxf((float)(end - beg), 1.0f));
        float4 b0 = *(const float4*)(bias + l16 * 8);
        float4 b1 = *(const float4*)(bias + l16 * 8 + 4);
        float4 o0, o1;
        o0.x = accA[0] * invd + b0.x; o0.y = accA[1] * invd + b0.y;
        o0.z = accA[2] * invd + b0.z; o0.w = accA[3] * invd + b0.w;
        o1.x = accA[4] * invd + b1.x; o1.y = accA[5] * invd + b1.y;
        o1.z = accA[6] * invd + b1.z; o1.w = accA[7] * invd + b1.w;
        *(float4*)(out + (long long)v * F + l16 * 8) = o0;
        *(float4*)(out + (long long)v * F + l16 * 8 + 4) = o1;
    }
}

extern "C" void kernel_launch(void* const* d_in, const int* in_sizes, int n_in,
                              void* d_out, int out_size, void* d_ws, size_t ws_size,
                              hipStream_t stream) {
    const float* x    = (const float*)d_in[0];
    const int*   src  = (const int*)d_in[1];
    const int*   dst  = (const int*)d_in[2];
    const float* W    = (const float*)d_in[3];
    const float* bias = (const float*)d_in[4];
    float* out = (float*)d_out;

    const int N = in_sizes[0] / F;        // 50000
    const int E = in_sizes[1];            // 800000
    const int NB = (N + 1023) / 1024;     // 49 (must be <= 64 for scan_rows)
    const int R = (N + RANGE - 1) / RANGE;

    size_t fixed_words = (size_t)N            // cnt_in
                       + (size_t)(N + 1)      // row_off
                       + (size_t)N            // inv_out
                       + (size_t)NB           // bsum
                       + (size_t)E            // csr_src
                       + ((size_t)N * F + 1) / 2;   // Y bf16
    int S = 64;
    while (S > 2 && (fixed_words + (size_t)2 * R * S * RANGE) * 4 > ws_size) S >>= 1;
    const int SLICE = (E + S - 1) / S;

    int*      part_src = (int*)d_ws;                       // [R*S*RANGE]
    int*      part_dst = part_src + (size_t)R * S * RANGE; // [R*S*RANGE]
    int*      cnt_in   = part_dst + (size_t)R * S * RANGE; // [N]
    int*      row_off  = cnt_in + N;                       // [N+1]
    float*    inv_out  = (float*)(row_off + N + 1);        // [N]
    int*      bsum     = (int*)(inv_out + N);              // [NB]
    int*      csr_src  = bsum + NB;                        // [E]
    ushort_t* Y        = (ushort_t*)(csr_src + E);         // [N*F] bf16

    const int hgrid = R * S;

    hist_both_kernel<<<hgrid, 256, 0, stream>>>(src, dst, part_src, part_dst, E, S, SLICE);
    reduce_all_kernel<<<NB, 256, 0, stream>>>(part_src, part_dst, inv_out, cnt_in, bsum, S, N);
    scan_rows_kernel<<<NB, 256, 0, stream>>>(cnt_in, bsum, row_off, N, E);
    fill_kernel<<<hgrid, 256, 0, stream>>>(src, dst, row_off, part_dst, csr_src, E, S, SLICE, N);
    gemm_kernel<<<(N + 31) / 32, 256, 0, stream>>>(x, W, inv_out, Y, N);
    gather_kernel<<<(N + 3) / 4, 256, 0, stream>>>(Y, csr_src, row_off, bias, out, N);
}

// Round 8
// 233.653 us; speedup vs baseline: 1.3400x; 1.3400x over previous
//
#include <hip/hip_runtime.h>

#define F 128
#define RANGE 12500   // nodes per LDS-histogram range

typedef unsigned short ushort_t;

__device__ inline float bf_lo(unsigned u) { return __uint_as_float(u << 16); }
__device__ inline float bf_hi(unsigned u) { return __uint_as_float(u & 0xffff0000u); }
__device__ inline ushort_t f2bf(float f) {          // RNE float->bf16
    unsigned u = __float_as_uint(f);
    return (ushort_t)((u + 0x7fff + ((u >> 16) & 1)) >> 16);
}

// ---- 1. fused src+dst LDS histograms (100 KB LDS, no global atomics) ----
__global__ __launch_bounds__(256)
void hist_both_kernel(const int* __restrict__ src, const int* __restrict__ dst,
                      int* __restrict__ part_src, int* __restrict__ part_dst,
                      int E, int S, int SLICE) {
    __shared__ int hs[RANGE];
    __shared__ int hd[RANGE];
    int b = blockIdx.x, t = threadIdx.x;
    int r = b / S, s = b % S;
    int lo = r * RANGE;
    for (int i = t; i < RANGE; i += 256) { hs[i] = 0; hd[i] = 0; }
    __syncthreads();
    int e0 = s * SLICE, e1 = min(e0 + SLICE, E);
    for (int e = e0 + t; e < e1; e += 256) {
        int vs = src[e] - lo;
        int vd = dst[e] - lo;
        if ((unsigned)vs < (unsigned)RANGE) atomicAdd(&hs[vs], 1);
        if ((unsigned)vd < (unsigned)RANGE) atomicAdd(&hd[vd], 1);
    }
    __syncthreads();
    int* ops = part_src + (size_t)b * RANGE;
    int* opd = part_dst + (size_t)b * RANGE;
    for (int i = t; i < RANGE; i += 256) { ops[i] = hs[i]; opd[i] = hd[i]; }
}

// ---- 2. reduction, 1 node/thread (196 blocks): inv_out, cnt_in,
//         per-slice prefix in part_dst, per-256-node partial sums psum ----
__global__ __launch_bounds__(256)
void reduce_all_kernel(const int* __restrict__ part_src, int* __restrict__ part_dst,
                       float* __restrict__ inv_out, int* __restrict__ cnt_in,
                       int* __restrict__ psum, int S, int N) {
    int b = blockIdx.x, t = threadIdx.x;
    int v = b * 256 + t;
    int run = 0;
    if (v < N) {
        int r = v / RANGE, vp = v % RANGE;
        const int* ps = part_src + (size_t)r * S * RANGE + vp;
        int sum = 0;
        for (int s = 0; s < S; ++s) sum += ps[(size_t)s * RANGE];
        inv_out[v] = rsqrtf(fmaxf((float)sum, 1.0f));
        int* pd = part_dst + (size_t)r * S * RANGE + vp;
        for (int s = 0; s < S; ++s) {
            int tv = pd[(size_t)s * RANGE];
            pd[(size_t)s * RANGE] = run;
            run += tv;
        }
        cnt_in[v] = run;
    }
    // block sum of in-degrees -> psum[b]
    int bl = run;
    #pragma unroll
    for (int off = 32; off > 0; off >>= 1) bl += __shfl_down(bl, off);
    __shared__ int ws[4];
    int lane = t & 63, w = t >> 6;
    if (lane == 0) ws[w] = bl;
    __syncthreads();
    if (t == 0) psum[b] = ws[0] + ws[1] + ws[2] + ws[3];
}

// ---- 3. row offsets: base = sum(psum[0..4b)), then block-local scan ----
// one block = 1024 nodes; psum entries = 256 nodes each; NP <= 256
__global__ __launch_bounds__(256)
void scan_rows_kernel(const int* __restrict__ cnt_in, const int* __restrict__ psum,
                      int* __restrict__ row_off, int N, int E, int NP) {
    int b = blockIdx.x, t = threadIdx.x;
    // block-reduce psum[0..4b)
    int pv = (t < 4 * b && t < NP) ? psum[t] : 0;
    #pragma unroll
    for (int off = 32; off > 0; off >>= 1) pv += __shfl_down(pv, off);
    __shared__ int red[4];
    int lane = t & 63, w = t >> 6;
    if (lane == 0) red[w] = pv;
    if (b == 0 && t == 0) row_off[N] = E;
    __syncthreads();
    int base = red[0] + red[1] + red[2] + red[3];

    int i0 = b * 1024 + t * 4;
    int v[4]; int s = 0;
    #pragma unroll
    for (int j = 0; j < 4; ++j) { int i = i0 + j; v[j] = (i < N) ? cnt_in[i] : 0; s += v[j]; }
    int incl = s;
    #pragma unroll
    for (int off = 1; off < 64; off <<= 1) {
        int u = __shfl_up(incl, off);
        if (lane >= off) incl += u;
    }
    __shared__ int wsum[4];
    if (lane == 63) wsum[w] = incl;
    __syncthreads();
    int wbase = 0;
    #pragma unroll
    for (int j = 0; j < 4; ++j) if (j < w) wbase += wsum[j];
    int run = base + wbase + (incl - s);
    #pragma unroll
    for (int j = 0; j < 4; ++j) {
        int i = i0 + j;
        if (i < N) { row_off[i] = run; run += v[j]; }
    }
}

// ---- 4. CSR fill with LDS cursors (no global atomics) ----
__global__ __launch_bounds__(256)
void fill_kernel(const int* __restrict__ src, const int* __restrict__ dst,
                 const int* __restrict__ row_off, const int* __restrict__ part_dst,
                 int* __restrict__ csr_src, int E, int S, int SLICE, int N) {
    __shared__ int cur[RANGE];
    int b = blockIdx.x, t = threadIdx.x;
    int r = b / S, s = b % S;
    int lo = r * RANGE;
    int hi = min(lo + RANGE, N);
    const int* pp = part_dst + (size_t)b * RANGE;
    for (int i = t; i < hi - lo; i += 256) cur[i] = row_off[lo + i] + pp[i];
    __syncthreads();
    int e0 = s * SLICE, e1 = min(e0 + SLICE, E);
    for (int e = e0 + t; e < e1; e += 256) {
        int d = dst[e] - lo;
        if ((unsigned)d < (unsigned)(hi - lo)) {
            int pos = atomicAdd(&cur[d], 1);       // LDS atomic
            csr_src[pos] = src[e];                 // plain store
        }
    }
}

// ---- 5. GEMM: Y = bf16( (x @ W) * inv_out[row] ) ----
__global__ __launch_bounds__(256)
void gemm_kernel(const float* __restrict__ x, const float* __restrict__ W,
                 const float* __restrict__ inv_out, ushort_t* __restrict__ Y, int N) {
    __shared__ float Ws[32 * 128];
    __shared__ float Hs[32 * 36];
    const int t = threadIdx.x;
    const int r0 = blockIdx.x * 32;
    const int tc = t & 31;
    const int tr = t >> 5;

    float4 a0 = {0,0,0,0}, a1 = {0,0,0,0}, a2 = {0,0,0,0}, a3 = {0,0,0,0};

    for (int kc = 0; kc < 4; ++kc) {
        const int k0 = kc * 32;
        #pragma unroll
        for (int j = 0; j < 16; ++j) {
            int i = t + 256 * j;
            int kk = i >> 7, c = i & 127;
            Ws[kk * 128 + c] = W[(k0 + kk) * F + c];
        }
        #pragma unroll
        for (int j = 0; j < 4; ++j) {
            int i = t + 256 * j;
            int r = i >> 5, kk = i & 31;
            int row = min(r0 + r, N - 1);
            Hs[kk * 36 + r] = x[(long long)row * F + k0 + kk];
        }
        __syncthreads();
        #pragma unroll
        for (int kk = 0; kk < 32; ++kk) {
            float4 hv = *(const float4*)&Hs[kk * 36 + 4 * tr];
            float4 wv = *(const float4*)&Ws[kk * 128 + 4 * tc];
            a0.x = fmaf(hv.x, wv.x, a0.x); a0.y = fmaf(hv.x, wv.y, a0.y);
            a0.z = fmaf(hv.x, wv.z, a0.z); a0.w = fmaf(hv.x, wv.w, a0.w);
            a1.x = fmaf(hv.y, wv.x, a1.x); a1.y = fmaf(hv.y, wv.y, a1.y);
            a1.z = fmaf(hv.y, wv.z, a1.z); a1.w = fmaf(hv.y, wv.w, a1.w);
            a2.x = fmaf(hv.z, wv.x, a2.x); a2.y = fmaf(hv.z, wv.y, a2.y);
            a2.z = fmaf(hv.z, wv.z, a2.z); a2.w = fmaf(hv.z, wv.w, a2.w);
            a3.x = fmaf(hv.w, wv.x, a3.x); a3.y = fmaf(hv.w, wv.y, a3.y);
            a3.z = fmaf(hv.w, wv.z, a3.z); a3.w = fmaf(hv.w, wv.w, a3.w);
        }
        __syncthreads();
    }

    float4 acc[4] = {a0, a1, a2, a3};
    #pragma unroll
    for (int i = 0; i < 4; ++i) {
        int row = r0 + 4 * tr + i;
        if (row < N) {
            float sc = inv_out[row];
            float4 o = acc[i];
            ushort4 yv;
            yv.x = f2bf(o.x * sc);
            yv.y = f2bf(o.y * sc);
            yv.z = f2bf(o.z * sc);
            yv.w = f2bf(o.w * sc);
            *(ushort4*)&Y[(long long)row * F + 4 * tc] = yv;
        }
    }
}

// ---- 6. gather: wave per node; quarter-waves (16 lanes x uint4 = 8 bf16) ----
__global__ __launch_bounds__(256)
void gather_kernel(const ushort_t* __restrict__ Y, const int* __restrict__ csr_src,
                   const int* __restrict__ row_off, const float* __restrict__ bias,
                   float* __restrict__ out, int N) {
    int v = blockIdx.x * 4 + (threadIdx.x >> 6);
    if (v >= N) return;
    int lane = threadIdx.x & 63;
    int q = lane >> 4;        // quarter 0..3
    int l16 = lane & 15;      // feats 8*l16 .. 8*l16+7
    int beg = row_off[v], end = row_off[v + 1];
    float accA[8] = {0,0,0,0,0,0,0,0};
    float accB[8] = {0,0,0,0,0,0,0,0};
    int j = beg + q;
    for (; j + 4 < end; j += 8) {
        int s0 = csr_src[j];
        int s1 = csr_src[j + 4];
        uint4 u0 = *(const uint4*)(Y + (size_t)s0 * F + l16 * 8);
        uint4 u1 = *(const uint4*)(Y + (size_t)s1 * F + l16 * 8);
        accA[0] += bf_lo(u0.x); accA[1] += bf_hi(u0.x);
        accA[2] += bf_lo(u0.y); accA[3] += bf_hi(u0.y);
        accA[4] += bf_lo(u0.z); accA[5] += bf_hi(u0.z);
        accA[6] += bf_lo(u0.w); accA[7] += bf_hi(u0.w);
        accB[0] += bf_lo(u1.x); accB[1] += bf_hi(u1.x);
        accB[2] += bf_lo(u1.y); accB[3] += bf_hi(u1.y);
        accB[4] += bf_lo(u1.z); accB[5] += bf_hi(u1.z);
        accB[6] += bf_lo(u1.w); accB[7] += bf_hi(u1.w);
    }
    if (j < end) {
        int s0 = csr_src[j];
        uint4 u0 = *(const uint4*)(Y + (size_t)s0 * F + l16 * 8);
        accA[0] += bf_lo(u0.x); accA[1] += bf_hi(u0.x);
        accA[2] += bf_lo(u0.y); accA[3] += bf_hi(u0.y);
        accA[4] += bf_lo(u0.z); accA[5] += bf_hi(u0.z);
        accA[6] += bf_lo(u0.w); accA[7] += bf_hi(u0.w);
    }
    #pragma unroll
    for (int i = 0; i < 8; ++i) {
        float a = accA[i] + accB[i];
        a += __shfl_xor(a, 16);
        a += __shfl_xor(a, 32);
        accA[i] = a;
    }
    if (q == 0) {
        float invd = rsqrtf(fmaxf((float)(end - beg), 1.0f));
        float4 b0 = *(const float4*)(bias + l16 * 8);
        float4 b1 = *(const float4*)(bias + l16 * 8 + 4);
        float4 o0, o1;
        o0.x = accA[0] * invd + b0.x; o0.y = accA[1] * invd + b0.y;
        o0.z = accA[2] * invd + b0.z; o0.w = accA[3] * invd + b0.w;
        o1.x = accA[4] * invd + b1.x; o1.y = accA[5] * invd + b1.y;
        o1.z = accA[6] * invd + b1.z; o1.w = accA[7] * invd + b1.w;
        *(float4*)(out + (long long)v * F + l16 * 8) = o0;
        *(float4*)(out + (long long)v * F + l16 * 8 + 4) = o1;
    }
}

extern "C" void kernel_launch(void* const* d_in, const int* in_sizes, int n_in,
                              void* d_out, int out_size, void* d_ws, size_t ws_size,
                              hipStream_t stream) {
    const float* x    = (const float*)d_in[0];
    const int*   src  = (const int*)d_in[1];
    const int*   dst  = (const int*)d_in[2];
    const float* W    = (const float*)d_in[3];
    const float* bias = (const float*)d_in[4];
    float* out = (float*)d_out;

    const int N = in_sizes[0] / F;        // 50000
    const int E = in_sizes[1];            // 800000
    const int NB = (N + 1023) / 1024;     // 49 scan blocks (<= 64)
    const int NP = (N + 255) / 256;       // 196 reduce blocks (<= 256)
    const int R = (N + RANGE - 1) / RANGE;

    size_t fixed_words = (size_t)N            // cnt_in
                       + (size_t)(N + 1)      // row_off
                       + (size_t)N            // inv_out
                       + (size_t)NP           // psum
                       + (size_t)E            // csr_src
                       + ((size_t)N * F + 1) / 2;   // Y bf16
    int S = 64;
    while (S > 2 && (fixed_words + (size_t)2 * R * S * RANGE) * 4 > ws_size) S >>= 1;
    const int SLICE = (E + S - 1) / S;

    int*      part_src = (int*)d_ws;                       // [R*S*RANGE]
    int*      part_dst = part_src + (size_t)R * S * RANGE; // [R*S*RANGE]
    int*      cnt_in   = part_dst + (size_t)R * S * RANGE; // [N]
    int*      row_off  = cnt_in + N;                       // [N+1]
    float*    inv_out  = (float*)(row_off + N + 1);        // [N]
    int*      psum     = (int*)(inv_out + N);              // [NP]
    int*      csr_src  = psum + NP;                        // [E]
    ushort_t* Y        = (ushort_t*)(csr_src + E);         // [N*F] bf16

    const int hgrid = R * S;

    hist_both_kernel<<<hgrid, 256, 0, stream>>>(src, dst, part_src, part_dst, E, S, SLICE);
    reduce_all_kernel<<<NP, 256, 0, stream>>>(part_src, part_dst, inv_out, cnt_in, psum, S, N);
    scan_rows_kernel<<<NB, 256, 0, stream>>>(cnt_in, psum, row_off, N, E, NP);
    fill_kernel<<<hgrid, 256, 0, stream>>>(src, dst, row_off, part_dst, csr_src, E, S, SLICE, N);
    gemm_kernel<<<(N + 31) / 32, 256, 0, stream>>>(x, W, inv_out, Y, N);
    gather_kernel<<<(N + 3) / 4, 256, 0, stream>>>(Y, csr_src, row_off, bias, out, N);
}

// Round 9
// 207.188 us; speedup vs baseline: 1.5112x; 1.1277x over previous
//
#include <hip/hip_runtime.h>

#define F 128
#define RANGE 12500   // nodes per LDS-histogram range
#define WT_LD 136     // f16 LDS stride for transposed W (16B-aligned, bank-uniform)

typedef unsigned short ushort_t;
typedef _Float16 half8 __attribute__((ext_vector_type(8)));
typedef float f32x4 __attribute__((ext_vector_type(4)));

__device__ inline float bf_lo(unsigned u) { return __uint_as_float(u << 16); }
__device__ inline float bf_hi(unsigned u) { return __uint_as_float(u & 0xffff0000u); }
__device__ inline ushort_t f2bf(float f) {          // RNE float->bf16
    unsigned u = __float_as_uint(f);
    return (ushort_t)((u + 0x7fff + ((u >> 16) & 1)) >> 16);
}

// ---- 1. packed src/dst LDS histogram: low16 = src count, high16 = dst count ----
// counts per (block,node) <= SLICE=12500 < 65536 -> no cross-field carry
__global__ __launch_bounds__(256)
void hist_both_kernel(const int* __restrict__ src, const int* __restrict__ dst,
                      int* __restrict__ part, int E, int S, int SLICE) {
    __shared__ int h[RANGE];
    int b = blockIdx.x, t = threadIdx.x;
    int r = b / S, s = b % S;
    int lo = r * RANGE;
    for (int i = t; i < RANGE; i += 256) h[i] = 0;
    __syncthreads();
    int e0 = s * SLICE, e1 = min(e0 + SLICE, E);
    for (int e = e0 + t; e < e1; e += 256) {
        int vs = src[e] - lo;
        int vd = dst[e] - lo;
        if ((unsigned)vs < (unsigned)RANGE) atomicAdd(&h[vs], 1);
        if ((unsigned)vd < (unsigned)RANGE) atomicAdd(&h[vd], 0x10000);
    }
    __syncthreads();
    int* outp = part + (size_t)b * RANGE;
    for (int i = t; i < RANGE; i += 256) outp[i] = h[i];
}

// ---- 2. reduction, 1 node/thread: inv_out, cnt_in, in-place dst prefix, psum ----
__global__ __launch_bounds__(256)
void reduce_all_kernel(int* __restrict__ part, float* __restrict__ inv_out,
                       int* __restrict__ cnt_in, int* __restrict__ psum,
                       int S, int N) {
    int b = blockIdx.x, t = threadIdx.x;
    int v = b * 256 + t;
    int run = 0;
    if (v < N) {
        int r = v / RANGE, vp = v % RANGE;
        int* p = part + (size_t)r * S * RANGE + vp;
        int sum_s = 0;
        for (int s = 0; s < S; ++s) {
            int tv = p[(size_t)s * RANGE];
            sum_s += tv & 0xffff;
            p[(size_t)s * RANGE] = run;    // dst exclusive prefix (full int)
            run += (tv >> 16);
        }
        inv_out[v] = rsqrtf(fmaxf((float)sum_s, 1.0f));
        cnt_in[v] = run;
    }
    int bl = run;
    #pragma unroll
    for (int off = 32; off > 0; off >>= 1) bl += __shfl_down(bl, off);
    __shared__ int ws[4];
    int lane = t & 63, w = t >> 6;
    if (lane == 0) ws[w] = bl;
    __syncthreads();
    if (t == 0) psum[b] = ws[0] + ws[1] + ws[2] + ws[3];
}

// ---- 3. row offsets: base = sum(psum[0..4b)), then block-local scan ----
__global__ __launch_bounds__(256)
void scan_rows_kernel(const int* __restrict__ cnt_in, const int* __restrict__ psum,
                      int* __restrict__ row_off, int N, int E, int NP) {
    int b = blockIdx.x, t = threadIdx.x;
    int pv = (t < 4 * b && t < NP) ? psum[t] : 0;
    #pragma unroll
    for (int off = 32; off > 0; off >>= 1) pv += __shfl_down(pv, off);
    __shared__ int red[4];
    int lane = t & 63, w = t >> 6;
    if (lane == 0) red[w] = pv;
    if (b == 0 && t == 0) row_off[N] = E;
    __syncthreads();
    int base = red[0] + red[1] + red[2] + red[3];

    int i0 = b * 1024 + t * 4;
    int v[4]; int s = 0;
    #pragma unroll
    for (int j = 0; j < 4; ++j) { int i = i0 + j; v[j] = (i < N) ? cnt_in[i] : 0; s += v[j]; }
    int incl = s;
    #pragma unroll
    for (int off = 1; off < 64; off <<= 1) {
        int u = __shfl_up(incl, off);
        if (lane >= off) incl += u;
    }
    __shared__ int wsum[4];
    if (lane == 63) wsum[w] = incl;
    __syncthreads();
    int wbase = 0;
    #pragma unroll
    for (int j = 0; j < 4; ++j) if (j < w) wbase += wsum[j];
    int run = base + wbase + (incl - s);
    #pragma unroll
    for (int j = 0; j < 4; ++j) {
        int i = i0 + j;
        if (i < N) { row_off[i] = run; run += v[j]; }
    }
}

// ---- 4. CSR fill with LDS cursors (no global atomics) ----
__global__ __launch_bounds__(256)
void fill_kernel(const int* __restrict__ src, const int* __restrict__ dst,
                 const int* __restrict__ row_off, const int* __restrict__ part,
                 int* __restrict__ csr_src, int E, int S, int SLICE, int N) {
    __shared__ int cur[RANGE];
    int b = blockIdx.x, t = threadIdx.x;
    int r = b / S, s = b % S;
    int lo = r * RANGE;
    int hi = min(lo + RANGE, N);
    const int* pp = part + (size_t)b * RANGE;
    for (int i = t; i < hi - lo; i += 256) cur[i] = row_off[lo + i] + pp[i];
    __syncthreads();
    int e0 = s * SLICE, e1 = min(e0 + SLICE, E);
    for (int e = e0 + t; e < e1; e += 256) {
        int d = dst[e] - lo;
        if ((unsigned)d < (unsigned)(hi - lo)) {
            int pos = atomicAdd(&cur[d], 1);       // LDS atomic
            csr_src[pos] = src[e];                 // plain store
        }
    }
}

// ---- 5. MFMA GEMM: Y = bf16( (x @ W) * inv_out[row] ), f16 inputs, fp32 acc ----
// block = 4 waves = 64 rows x 128 cols; W staged transposed f16 in LDS
__global__ __launch_bounds__(256)
void gemm_kernel(const float* __restrict__ x, const float* __restrict__ W,
                 const float* __restrict__ inv_out, ushort_t* __restrict__ Y, int N) {
    __shared__ _Float16 Wt[128 * WT_LD];   // Wt[col][k], 34.8 KB
    const int t = threadIdx.x;
    for (int i = t; i < 128 * 128; i += 256) {
        int k = i >> 7, c = i & 127;       // coalesced read of W[k][c]
        Wt[c * WT_LD + k] = (_Float16)W[i];
    }
    __syncthreads();

    const int wv = t >> 6;                 // wave 0..3
    const int l  = t & 63;
    const int m  = l & 15;                 // A row within tile / B col
    const int q  = l >> 4;                 // k-quad
    const int r0w = blockIdx.x * 64 + wv * 16;
    const int rowload = min(r0w + m, N - 1);
    const float* xr = x + (size_t)rowload * F;

    f32x4 acc[8] = {};                     // 8 col-tiles of 16
    #pragma unroll
    for (int k0 = 0; k0 < 128; k0 += 32) {
        const int kk = k0 + q * 8;
        float4 xa = *(const float4*)(xr + kk);
        float4 xb = *(const float4*)(xr + kk + 4);
        half8 a;
        a[0] = (_Float16)xa.x; a[1] = (_Float16)xa.y;
        a[2] = (_Float16)xa.z; a[3] = (_Float16)xa.w;
        a[4] = (_Float16)xb.x; a[5] = (_Float16)xb.y;
        a[6] = (_Float16)xb.z; a[7] = (_Float16)xb.w;
        #pragma unroll
        for (int ct = 0; ct < 8; ++ct) {
            half8 bfr = *(const half8*)&Wt[(ct * 16 + m) * WT_LD + kk];
            acc[ct] = __builtin_amdgcn_mfma_f32_16x16x32_f16(a, bfr, acc[ct], 0, 0, 0);
        }
    }

    // C/D layout: col = lane&15 (= m), row = q*4 + reg
    float sc[4]; int rvalid[4];
    #pragma unroll
    for (int reg = 0; reg < 4; ++reg) {
        int rr = r0w + q * 4 + reg;
        rvalid[reg] = rr < N;
        sc[reg] = inv_out[min(rr, N - 1)];
    }
    #pragma unroll
    for (int ct = 0; ct < 8; ++ct) {
        #pragma unroll
        for (int reg = 0; reg < 4; ++reg) {
            if (rvalid[reg]) {
                int rr = r0w + q * 4 + reg;
                Y[(size_t)rr * F + ct * 16 + m] = f2bf(acc[ct][reg] * sc[reg]);
            }
        }
    }
}

// ---- 6. gather: wave per node; quarter-waves (16 lanes x uint4 = 8 bf16) ----
__global__ __launch_bounds__(256)
void gather_kernel(const ushort_t* __restrict__ Y, const int* __restrict__ csr_src,
                   const int* __restrict__ row_off, const float* __restrict__ bias,
                   float* __restrict__ out, int N) {
    int v = blockIdx.x * 4 + (threadIdx.x >> 6);
    if (v >= N) return;
    int lane = threadIdx.x & 63;
    int q = lane >> 4;        // quarter 0..3
    int l16 = lane & 15;      // feats 8*l16 .. 8*l16+7
    int beg = row_off[v], end = row_off[v + 1];
    float accA[8] = {0,0,0,0,0,0,0,0};
    float accB[8] = {0,0,0,0,0,0,0,0};
    int j = beg + q;
    for (; j + 4 < end; j += 8) {
        int s0 = csr_src[j];
        int s1 = csr_src[j + 4];
        uint4 u0 = *(const uint4*)(Y + (size_t)s0 * F + l16 * 8);
        uint4 u1 = *(const uint4*)(Y + (size_t)s1 * F + l16 * 8);
        accA[0] += bf_lo(u0.x); accA[1] += bf_hi(u0.x);
        accA[2] += bf_lo(u0.y); accA[3] += bf_hi(u0.y);
        accA[4] += bf_lo(u0.z); accA[5] += bf_hi(u0.z);
        accA[6] += bf_lo(u0.w); accA[7] += bf_hi(u0.w);
        accB[0] += bf_lo(u1.x); accB[1] += bf_hi(u1.x);
        accB[2] += bf_lo(u1.y); accB[3] += bf_hi(u1.y);
        accB[4] += bf_lo(u1.z); accB[5] += bf_hi(u1.z);
        accB[6] += bf_lo(u1.w); accB[7] += bf_hi(u1.w);
    }
    if (j < end) {
        int s0 = csr_src[j];
        uint4 u0 = *(const uint4*)(Y + (size_t)s0 * F + l16 * 8);
        accA[0] += bf_lo(u0.x); accA[1] += bf_hi(u0.x);
        accA[2] += bf_lo(u0.y); accA[3] += bf_hi(u0.y);
        accA[4] += bf_lo(u0.z); accA[5] += bf_hi(u0.z);
        accA[6] += bf_lo(u0.w); accA[7] += bf_hi(u0.w);
    }
    #pragma unroll
    for (int i = 0; i < 8; ++i) {
        float a = accA[i] + accB[i];
        a += __shfl_xor(a, 16);
        a += __shfl_xor(a, 32);
        accA[i] = a;
    }
    if (q == 0) {
        float invd = rsqrtf(fmaxf((float)(end - beg), 1.0f));
        float4 b0 = *(const float4*)(bias + l16 * 8);
        float4 b1 = *(const float4*)(bias + l16 * 8 + 4);
        float4 o0, o1;
        o0.x = accA[0] * invd + b0.x; o0.y = accA[1] * invd + b0.y;
        o0.z = accA[2] * invd + b0.z; o0.w = accA[3] * invd + b0.w;
        o1.x = accA[4] * invd + b1.x; o1.y = accA[5] * invd + b1.y;
        o1.z = accA[6] * invd + b1.z; o1.w = accA[7] * invd + b1.w;
        *(float4*)(out + (long long)v * F + l16 * 8) = o0;
        *(float4*)(out + (long long)v * F + l16 * 8 + 4) = o1;
    }
}

extern "C" void kernel_launch(void* const* d_in, const int* in_sizes, int n_in,
                              void* d_out, int out_size, void* d_ws, size_t ws_size,
                              hipStream_t stream) {
    const float* x    = (const float*)d_in[0];
    const int*   src  = (const int*)d_in[1];
    const int*   dst  = (const int*)d_in[2];
    const float* W    = (const float*)d_in[3];
    const float* bias = (const float*)d_in[4];
    float* out = (float*)d_out;

    const int N = in_sizes[0] / F;        // 50000
    const int E = in_sizes[1];            // 800000
    const int NB = (N + 1023) / 1024;     // 49 scan blocks (<= 64)
    const int NP = (N + 255) / 256;       // 196 reduce blocks (<= 256)
    const int R = (N + RANGE - 1) / RANGE;

    size_t fixed_words = (size_t)N            // cnt_in
                       + (size_t)(N + 1)      // row_off
                       + (size_t)N            // inv_out
                       + (size_t)NP           // psum
                       + (size_t)E            // csr_src
                       + ((size_t)N * F + 1) / 2;   // Y bf16
    int S = 64;
    while (S > 2 && (fixed_words + (size_t)R * S * RANGE) * 4 > ws_size) S >>= 1;
    const int SLICE = (E + S - 1) / S;

    int*      part    = (int*)d_ws;                       // [R*S*RANGE] packed
    int*      cnt_in  = part + (size_t)R * S * RANGE;     // [N]
    int*      row_off = cnt_in + N;                       // [N+1]
    float*    inv_out = (float*)(row_off + N + 1);        // [N]
    int*      psum    = (int*)(inv_out + N);              // [NP]
    int*      csr_src = psum + NP;                        // [E]
    ushort_t* Y       = (ushort_t*)(csr_src + E);         // [N*F] bf16

    const int hgrid = R * S;

    hist_both_kernel<<<hgrid, 256, 0, stream>>>(src, dst, part, E, S, SLICE);
    reduce_all_kernel<<<NP, 256, 0, stream>>>(part, inv_out, cnt_in, psum, S, N);
    scan_rows_kernel<<<NB, 256, 0, stream>>>(cnt_in, psum, row_off, N, E, NP);
    fill_kernel<<<hgrid, 256, 0, stream>>>(src, dst, row_off, part, csr_src, E, S, SLICE, N);
    gemm_kernel<<<(N + 63) / 64, 256, 0, stream>>>(x, W, inv_out, Y, N);
    gather_kernel<<<(N + 3) / 4, 256, 0, stream>>>(Y, csr_src, row_off, bias, out, N);
}